// Round 1
// baseline (547.151 us; speedup 1.0000x reference)
//
#include <hip/hip_runtime.h>

// Local2d: out[b,o,h,w] = sum_{i,ky,kx} weight[o,h,w,i,ky,kx]*xpad[b,i,h+ky-1,w+kx-1] + bias
// B=64, C_IN=64, C_OUT=128, K=3, H=W=32.
//
// Two kernels:
//  1) prep_kernel (im2col): x -> P in d_ws. P[loc][tc 18][mt 4][lane 64][j 8] bf16
//     (75.5 MB), the exact MFMA A-fragment byte order for k = i*9+ky*3+kx. (unchanged)
//  2) local2d_kernel v2: per-loc GEMM M=64,N=128,K=576 in 3 chunks of 192.
//     - og merged: grid 1024 (one block per loc), P read ONCE (was twice).
//     - A: double-buffered global_load_lds (2x24,576 B) -> chunk c+1 in flight
//       under chunk c's compute; barrier drain nearly free.
//     - W: NO LDS. Per-lane direct global B-fragments (o=nt*16+ll, k=c*192+t*32+q*8
//       -> 8 contiguous floats, two dwordx4 w/ immediate offsets). x4 wave reuse
//       of each 128B line served by L2. Removes the W staging phase entirely.
//     LDS 49,152 B -> 3 blocks/CU. XCD swizzle unchanged (h-row group per XCD so
//     the 16 blocks sharing each 64 B out-line merge in one L2).

typedef __bf16  bf16x8  __attribute__((ext_vector_type(8)));
typedef float   floatx4 __attribute__((ext_vector_type(4)));

static __device__ inline bf16x8 cvt8(floatx4 a, floatx4 b) {
    bf16x8 r;
    r[0] = (__bf16)a[0]; r[1] = (__bf16)a[1]; r[2] = (__bf16)a[2]; r[3] = (__bf16)a[3];
    r[4] = (__bf16)b[0]; r[5] = (__bf16)b[1]; r[6] = (__bf16)b[2]; r[7] = (__bf16)b[3];
    return r;
}

// ---------------- im2col prep (unchanged) ----------------
// grid 1024 = h(32) x ig(8) x bq(4); block 256.
__global__ __launch_bounds__(256, 3) void prep_kernel(
    const float* __restrict__ x, __bf16* __restrict__ P)
{
    __shared__ float xl[16 * 772];   // [bl][il*96 + ky*32 + w], bl-stride 772 (align+bank)

    const int tid = threadIdx.x;
    const int bid = blockIdx.x;
    const int bq = bid & 3;          // mt  (b = bq*16 + bl)
    const int ig = (bid >> 2) & 7;   // i-group of 8 -> 9 k-octets
    const int h  = bid >> 5;

    // stage 384 rows of 32 floats (zeros for OOB y)
    #pragma unroll
    for (int it = 0; it < 12; ++it) {
        int g   = tid + (it << 8);       // 0..3071
        int row = g >> 3;                // 0..383 = bl*24 + il*3 + ky
        int sub = g & 7;
        int bl  = row / 24;
        int rem = row - bl * 24;
        int il  = rem / 3;
        int ky  = rem - il * 3;
        int y   = h + ky - 1;
        floatx4 v = {0.f, 0.f, 0.f, 0.f};
        if ((unsigned)y < 32u) {
            const float* src = x + (((size_t)(bq * 16 + bl) * 64 + ig * 8 + il) << 10)
                                 + y * 32 + (sub << 2);
            v = *(const floatx4*)src;
        }
        *(floatx4*)&xl[bl * 772 + il * 96 + ky * 32 + (sub << 2)] = v;
    }
    __syncthreads();

    const int lane = tid & 63;
    const int wv = tid >> 6;
    const int bl = lane & 15;
    const int qq = lane >> 4;

    // 288 (w,kol) pairs x 16 bl; 16 pairs per iter (4 waves x 4 quads)
    #pragma unroll 2
    for (int it = 0; it < 18; ++it) {
        int pr  = (it << 4) + (wv << 2) + qq;   // 0..287
        int w   = pr / 9;
        int kol = pr - w * 9;                   // 0..8
        int ko  = ig * 9 + kol;                 // global k-octet 0..71
        bf16x8 piece;
        #pragma unroll
        for (int j = 0; j < 8; ++j) {
            int klocal = (kol << 3) + j;        // 0..71 within i-group
            int il = klocal / 9;
            int p  = klocal - il * 9;
            int ky = p / 3;
            int kx = p - ky * 3;
            int xc = w + kx - 1;
            float v = ((unsigned)xc < 32u) ? xl[bl * 772 + il * 96 + ky * 32 + xc] : 0.0f;
            piece[j] = (__bf16)v;
        }
        int loc   = (h << 5) + w;
        int idx16 = ((ko >> 2) << 8) + (bq << 6) + ((ko & 3) << 4) + bl;
        *(bf16x8*)&P[((size_t)loc * 4608 + idx16) * 8] = piece;
    }
}

// ---------------- main GEMM v2 ----------------
__global__ __launch_bounds__(256, 3) void local2d_kernel(
    const __bf16* __restrict__ P,      // patches, fragment layout
    const float* __restrict__ weight,  // [128,32,32,64,3,3]
    const float* __restrict__ bias,    // [128,32,32]
    float* __restrict__ out)           // [64,128,32,32]
{
    __shared__ __bf16 alds[2][12288];  // 2 x 24,576 B double-buffered A

    const int tid  = threadIdx.x;
    const int lane = tid & 63;
    const int wv   = tid >> 6;      // m-tile
    const int ll   = lane & 15;
    const int q    = lane >> 4;

    // bid = [hl 2][w 5][xcd 3]: XCD owns 4 h-rows; out-line-mates co-XCD.
    const int bid = blockIdx.x;
    const int xcd = bid & 7;
    const int w   = (bid >> 3) & 31;
    const int hl  = bid >> 8;
    const int h   = (xcd << 2) + hl;
    const int loc = (h << 5) + w;

    const __bf16* Ploc = P + (size_t)loc * 36864;   // 36,864 bf16 per loc

    // per-lane W fragment base: o = nt*16 + ll ; k = c*192 + t*32 + q*8
    // weight offset(o,loc,k) = (o*1024 + loc)*576 + k  floats
    const float* wlane = weight + ((size_t)ll * 1024 + loc) * 576 + (q << 3);
    const float* wptr[8];
    #pragma unroll
    for (int nt = 0; nt < 8; ++nt) wptr[nt] = wlane + (size_t)nt * 9437184;  // 16*1024*576

    floatx4 acc[8];
    #pragma unroll
    for (int nt = 0; nt < 8; ++nt) acc[nt] = (floatx4){0.f, 0.f, 0.f, 0.f};

    // ---- prologue: stage chunk 0 -> buf 0 (async, 24,576 B) ----
    #pragma unroll
    for (int it = 0; it < 6; ++it) {
        const __bf16* g = Ploc + ((((it << 2) + wv) << 6) | lane) * 8;
        __builtin_amdgcn_global_load_lds(
            (const __attribute__((address_space(1))) unsigned int*)g,
            (__attribute__((address_space(3))) unsigned int*)&alds[0][(((it << 2) + wv) << 6) * 8],
            16, 0, 0);
    }
    __syncthreads();

    #pragma unroll
    for (int c = 0; c < 3; ++c) {
        // ---- issue next chunk's A while computing this one ----
        if (c < 2) {
            #pragma unroll
            for (int it = 0; it < 6; ++it) {
                const __bf16* g = Ploc + (c + 1) * 12288 + ((((it << 2) + wv) << 6) | lane) * 8;
                __builtin_amdgcn_global_load_lds(
                    (const __attribute__((address_space(1))) unsigned int*)g,
                    (__attribute__((address_space(3))) unsigned int*)&alds[(c + 1) & 1][(((it << 2) + wv) << 6) * 8],
                    16, 0, 0);
            }
        }
        // ---- K loop: 6 steps of K=32; W streamed per-lane from global ----
        #pragma unroll
        for (int t = 0; t < 6; ++t) {
            bf16x8 af = *(const bf16x8*)&alds[c & 1][((((t << 2) + wv) << 6) | lane) * 8];
            #pragma unroll
            for (int nt = 0; nt < 8; ++nt) {
                const float* src = wptr[nt] + c * 192 + t * 32;   // imm-offset folds
                floatx4 va = *(const floatx4*)src;
                floatx4 vb = *(const floatx4*)(src + 4);
                acc[nt] = __builtin_amdgcn_mfma_f32_16x16x32_bf16(af, cvt8(va, vb), acc[nt], 0, 0, 0);
            }
        }
        if (c < 2) __syncthreads();   // drains this wave's gll; buf[c^1] ready, buf[c] free
    }

    // ---- epilogue: C/D col=lane&15 -> o, row=q*4+r -> b ----
    #pragma unroll
    for (int nt = 0; nt < 8; ++nt) {
        int o = (nt << 4) + ll;
        float bv = bias[((size_t)o << 10) + loc];
        #pragma unroll
        for (int r = 0; r < 4; ++r) {
            int m = (wv << 4) + (q << 2) + r;
            out[(((size_t)m << 7) + o) * 1024 + loc] = acc[nt][r] + bv;
        }
    }
}

extern "C" void kernel_launch(void* const* d_in, const int* in_sizes, int n_in,
                              void* d_out, int out_size, void* d_ws, size_t ws_size,
                              hipStream_t stream) {
    const float* x  = (const float*)d_in[0];
    const float* wt = (const float*)d_in[1];
    const float* bi = (const float*)d_in[2];
    float* out = (float*)d_out;
    __bf16* P = (__bf16*)d_ws;   // needs 75,497,472 B
    prep_kernel<<<dim3(1024), dim3(256), 0, stream>>>(x, P);
    local2d_kernel<<<dim3(1024), dim3(256), 0, stream>>>(P, wt, bi, out);
}

// Round 2
// 516.077 us; speedup vs baseline: 1.0602x; 1.0602x over previous
//
#include <hip/hip_runtime.h>

// Local2d: out[b,o,h,w] = sum_{i,ky,kx} weight[o,h,w,i,ky,kx]*xpad[b,i,h+ky-1,w+kx-1] + bias
// B=64, C_IN=64, C_OUT=128, K=3, H=W=32.
//
// Two kernels:
//  1) prep_kernel (im2col): x -> P in d_ws. P[loc][tc 18][mt 4][lane 64][j 8] bf16
//     (75.5 MB), the exact MFMA A-fragment byte order for k = i*9+ky*3+kx. (unchanged)
//  2) local2d_kernel v3: per-loc GEMM M=64,N=128,K=576 in 3 chunks of 192.
//     - og merged (P read once); A double-buffered via global_load_lds (2x24,576 B).
//     - waves split 2x2: wm -> m-frags {2wm,2wm+1}, wn -> o-half (4 nt). W per-lane
//       direct from global, REGISTER DOUBLE-BUFFERED: issue t+1's 8 dwordx4 before
//       t's MFMA cluster -> 8-16 loads in flight per wave (v2 had ~1: 19% BW,
//       1 HBM latency per pair). 2x W redundancy (was 4x) -> L2 request ~12 TB/s.
//     LDS 49,152 B -> 3 blocks/CU. XCD swizzle: h-row group per XCD so the 16
//     blocks sharing each 64 B out-line merge in one L2.

typedef __bf16  bf16x8  __attribute__((ext_vector_type(8)));
typedef float   floatx4 __attribute__((ext_vector_type(4)));

static __device__ inline bf16x8 cvt8(floatx4 a, floatx4 b) {
    bf16x8 r;
    r[0] = (__bf16)a[0]; r[1] = (__bf16)a[1]; r[2] = (__bf16)a[2]; r[3] = (__bf16)a[3];
    r[4] = (__bf16)b[0]; r[5] = (__bf16)b[1]; r[6] = (__bf16)b[2]; r[7] = (__bf16)b[3];
    return r;
}

// ---------------- im2col prep (unchanged) ----------------
// grid 1024 = h(32) x ig(8) x bq(4); block 256.
__global__ __launch_bounds__(256, 3) void prep_kernel(
    const float* __restrict__ x, __bf16* __restrict__ P)
{
    __shared__ float xl[16 * 772];   // [bl][il*96 + ky*32 + w], bl-stride 772 (align+bank)

    const int tid = threadIdx.x;
    const int bid = blockIdx.x;
    const int bq = bid & 3;          // mt  (b = bq*16 + bl)
    const int ig = (bid >> 2) & 7;   // i-group of 8 -> 9 k-octets
    const int h  = bid >> 5;

    // stage 384 rows of 32 floats (zeros for OOB y)
    #pragma unroll
    for (int it = 0; it < 12; ++it) {
        int g   = tid + (it << 8);       // 0..3071
        int row = g >> 3;                // 0..383 = bl*24 + il*3 + ky
        int sub = g & 7;
        int bl  = row / 24;
        int rem = row - bl * 24;
        int il  = rem / 3;
        int ky  = rem - il * 3;
        int y   = h + ky - 1;
        floatx4 v = {0.f, 0.f, 0.f, 0.f};
        if ((unsigned)y < 32u) {
            const float* src = x + (((size_t)(bq * 16 + bl) * 64 + ig * 8 + il) << 10)
                                 + y * 32 + (sub << 2);
            v = *(const floatx4*)src;
        }
        *(floatx4*)&xl[bl * 772 + il * 96 + ky * 32 + (sub << 2)] = v;
    }
    __syncthreads();

    const int lane = tid & 63;
    const int wv = tid >> 6;
    const int bl = lane & 15;
    const int qq = lane >> 4;

    // 288 (w,kol) pairs x 16 bl; 16 pairs per iter (4 waves x 4 quads)
    #pragma unroll 2
    for (int it = 0; it < 18; ++it) {
        int pr  = (it << 4) + (wv << 2) + qq;   // 0..287
        int w   = pr / 9;
        int kol = pr - w * 9;                   // 0..8
        int ko  = ig * 9 + kol;                 // global k-octet 0..71
        bf16x8 piece;
        #pragma unroll
        for (int j = 0; j < 8; ++j) {
            int klocal = (kol << 3) + j;        // 0..71 within i-group
            int il = klocal / 9;
            int p  = klocal - il * 9;
            int ky = p / 3;
            int kx = p - ky * 3;
            int xc = w + kx - 1;
            float v = ((unsigned)xc < 32u) ? xl[bl * 772 + il * 96 + ky * 32 + xc] : 0.0f;
            piece[j] = (__bf16)v;
        }
        int loc   = (h << 5) + w;
        int idx16 = ((ko >> 2) << 8) + (bq << 6) + ((ko & 3) << 4) + bl;
        *(bf16x8*)&P[((size_t)loc * 4608 + idx16) * 8] = piece;
    }
}

// ---------------- main GEMM v3 ----------------
__global__ __launch_bounds__(256, 3) void local2d_kernel(
    const __bf16* __restrict__ P,      // patches, fragment layout
    const float* __restrict__ weight,  // [128,32,32,64,3,3]
    const float* __restrict__ bias,    // [128,32,32]
    float* __restrict__ out)           // [64,128,32,32]
{
    __shared__ __bf16 alds[2][12288];  // 2 x 24,576 B double-buffered A

    const int tid  = threadIdx.x;
    const int lane = tid & 63;
    const int wv   = tid >> 6;
    const int wm   = wv & 1;        // m-half: frags {2wm, 2wm+1}
    const int wn   = wv >> 1;       // o-half: nt in {4wn..4wn+3}
    const int ll   = lane & 15;
    const int q    = lane >> 4;

    // bid = [hl 2][w 5][xcd 3]: XCD owns 4 h-rows; out-line-mates co-XCD.
    const int bid = blockIdx.x;
    const int xcd = bid & 7;
    const int w   = (bid >> 3) & 31;
    const int hl  = bid >> 8;
    const int h   = (xcd << 2) + hl;
    const int loc = (h << 5) + w;

    const __bf16* Ploc = P + (size_t)loc * 36864;   // 36,864 bf16 per loc

    // per-lane W fragment pointers: o = (4wn+j)*16 + ll ; k = c*192 + t*32 + q*8
    // weight offset(o,loc,k) = (o*1024 + loc)*576 + k  floats
    const float* wbase = weight + (size_t)ll * 589824 + (size_t)loc * 576 + (q << 3);
    const float* wp[4];
    #pragma unroll
    for (int j = 0; j < 4; ++j)
        wp[j] = wbase + (size_t)((wn << 2) + j) * 9437184;   // 16*1024*576

    floatx4 acc0[4], acc1[4];
    #pragma unroll
    for (int j = 0; j < 4; ++j) {
        acc0[j] = (floatx4){0.f, 0.f, 0.f, 0.f};
        acc1[j] = (floatx4){0.f, 0.f, 0.f, 0.f};
    }

    // ---- prologue: stage chunk 0 -> buf 0 (async, 24,576 B) ----
    #pragma unroll
    for (int it = 0; it < 6; ++it) {
        const __bf16* g = Ploc + ((((it << 2) + wv) << 6) | lane) * 8;
        __builtin_amdgcn_global_load_lds(
            (const __attribute__((address_space(1))) unsigned int*)g,
            (__attribute__((address_space(3))) unsigned int*)&alds[0][(((it << 2) + wv) << 6) * 8],
            16, 0, 0);
    }
    __syncthreads();

    #pragma unroll
    for (int c = 0; c < 3; ++c) {
        // ---- issue next chunk's A while computing this one ----
        if (c < 2) {
            #pragma unroll
            for (int it = 0; it < 6; ++it) {
                const __bf16* g = Ploc + (c + 1) * 12288 + ((((it << 2) + wv) << 6) | lane) * 8;
                __builtin_amdgcn_global_load_lds(
                    (const __attribute__((address_space(1))) unsigned int*)g,
                    (__attribute__((address_space(3))) unsigned int*)&alds[(c + 1) & 1][(((it << 2) + wv) << 6) * 8],
                    16, 0, 0);
            }
        }

        // ---- preload W pairs for t=0 (8 dwordx4 in flight) ----
        floatx4 cva[4], cvb[4], nva[4], nvb[4];
        #pragma unroll
        for (int j = 0; j < 4; ++j) {
            const float* s = wp[j] + c * 192;
            cva[j] = *(const floatx4*)s;
            cvb[j] = *(const floatx4*)(s + 4);
        }

        // ---- K loop: 6 steps of K=32; W register double-buffered ----
        #pragma unroll
        for (int t = 0; t < 6; ++t) {
            bf16x8 af0 = *(const bf16x8*)&alds[c & 1][((((t << 2) + (wm << 1)) << 6) | lane) * 8];
            bf16x8 af1 = *(const bf16x8*)&alds[c & 1][((((t << 2) + (wm << 1) + 1) << 6) | lane) * 8];
            if (t < 5) {   // issue t+1's loads BEFORE t's MFMAs
                #pragma unroll
                for (int j = 0; j < 4; ++j) {
                    const float* s = wp[j] + c * 192 + (t + 1) * 32;
                    nva[j] = *(const floatx4*)s;
                    nvb[j] = *(const floatx4*)(s + 4);
                }
            }
            #pragma unroll
            for (int j = 0; j < 4; ++j) {
                bf16x8 bw = cvt8(cva[j], cvb[j]);
                acc0[j] = __builtin_amdgcn_mfma_f32_16x16x32_bf16(af0, bw, acc0[j], 0, 0, 0);
                acc1[j] = __builtin_amdgcn_mfma_f32_16x16x32_bf16(af1, bw, acc1[j], 0, 0, 0);
            }
            if (t < 5) {
                #pragma unroll
                for (int j = 0; j < 4; ++j) { cva[j] = nva[j]; cvb[j] = nvb[j]; }
            }
        }
        if (c < 2) __syncthreads();   // buf[c^1] staged; buf[c] free for overwrite
    }

    // ---- epilogue: C/D col=lane&15 -> o, row=q*4+r -> b ----
    #pragma unroll
    for (int fi = 0; fi < 2; ++fi) {
        #pragma unroll
        for (int j = 0; j < 4; ++j) {
            int o = (((wn << 2) + j) << 4) + ll;
            float bv = bias[((size_t)o << 10) + loc];
            #pragma unroll
            for (int r = 0; r < 4; ++r) {
                int m = (((wm << 1) + fi) << 4) + (q << 2) + r;
                float v = (fi == 0 ? acc0[j][r] : acc1[j][r]) + bv;
                out[(((size_t)m << 7) + o) * 1024 + loc] = v;
            }
        }
    }
}

extern "C" void kernel_launch(void* const* d_in, const int* in_sizes, int n_in,
                              void* d_out, int out_size, void* d_ws, size_t ws_size,
                              hipStream_t stream) {
    const float* x  = (const float*)d_in[0];
    const float* wt = (const float*)d_in[1];
    const float* bi = (const float*)d_in[2];
    float* out = (float*)d_out;
    __bf16* P = (__bf16*)d_ws;   // needs 75,497,472 B
    prep_kernel<<<dim3(1024), dim3(256), 0, stream>>>(x, P);
    local2d_kernel<<<dim3(1024), dim3(256), 0, stream>>>(P, wt, bi, out);
}

// Round 3
// 506.603 us; speedup vs baseline: 1.0800x; 1.0187x over previous
//
#include <hip/hip_runtime.h>

// Local2d: out[b,o,h,w] = sum_{i,ky,kx} weight[o,h,w,i,ky,kx]*xpad[b,i,h+ky-1,w+kx-1] + bias
// B=64, C_IN=64, C_OUT=128, K=3, H=W=32.
//
// Two kernels:
//  1) prep_kernel (im2col): x -> P in d_ws. P[loc][tc 18][mt 4][lane 64][j 8] bf16
//     (75.5 MB), the exact MFMA A-fragment byte order for k = i*9+ky*3+kx. (unchanged)
//  2) local2d_kernel v4: per-loc GEMM M=64,N=128,K=576 in 3 chunks of 192.
//     - og merged (P read once); A double-buffered via global_load_lds (2x24,576 B).
//     - waves split 2x2: wm -> m-frags {2wm,2wm+1}, wn -> o-half (4 nt).
//     - W per-lane direct from global, 3-STAGE rotating register pipeline:
//       prefetch distance = 2 t-iterations (~250 cyc issued work vs v3's ~120),
//       x3 waves/SIMD TLP -> covers L2 (~200cy) and most HBM (~900cy) latency.
//       v3 (2-stage) still exposed latency-120cy per t-step -> 162 us.
//     VGPR ~156 (<168 cap at 3 waves/EU); LDS 49,152 B -> 3 blocks/CU.
//     XCD swizzle: h-row group per XCD so the 16 blocks sharing each 64 B
//     out-line merge in one L2.

typedef __bf16  bf16x8  __attribute__((ext_vector_type(8)));
typedef float   floatx4 __attribute__((ext_vector_type(4)));

static __device__ inline bf16x8 cvt8(floatx4 a, floatx4 b) {
    bf16x8 r;
    r[0] = (__bf16)a[0]; r[1] = (__bf16)a[1]; r[2] = (__bf16)a[2]; r[3] = (__bf16)a[3];
    r[4] = (__bf16)b[0]; r[5] = (__bf16)b[1]; r[6] = (__bf16)b[2]; r[7] = (__bf16)b[3];
    return r;
}

// ---------------- im2col prep (unchanged) ----------------
// grid 1024 = h(32) x ig(8) x bq(4); block 256.
__global__ __launch_bounds__(256, 3) void prep_kernel(
    const float* __restrict__ x, __bf16* __restrict__ P)
{
    __shared__ float xl[16 * 772];   // [bl][il*96 + ky*32 + w], bl-stride 772 (align+bank)

    const int tid = threadIdx.x;
    const int bid = blockIdx.x;
    const int bq = bid & 3;          // mt  (b = bq*16 + bl)
    const int ig = (bid >> 2) & 7;   // i-group of 8 -> 9 k-octets
    const int h  = bid >> 5;

    // stage 384 rows of 32 floats (zeros for OOB y)
    #pragma unroll
    for (int it = 0; it < 12; ++it) {
        int g   = tid + (it << 8);       // 0..3071
        int row = g >> 3;                // 0..383 = bl*24 + il*3 + ky
        int sub = g & 7;
        int bl  = row / 24;
        int rem = row - bl * 24;
        int il  = rem / 3;
        int ky  = rem - il * 3;
        int y   = h + ky - 1;
        floatx4 v = {0.f, 0.f, 0.f, 0.f};
        if ((unsigned)y < 32u) {
            const float* src = x + (((size_t)(bq * 16 + bl) * 64 + ig * 8 + il) << 10)
                                 + y * 32 + (sub << 2);
            v = *(const floatx4*)src;
        }
        *(floatx4*)&xl[bl * 772 + il * 96 + ky * 32 + (sub << 2)] = v;
    }
    __syncthreads();

    const int lane = tid & 63;
    const int wv = tid >> 6;
    const int bl = lane & 15;
    const int qq = lane >> 4;

    // 288 (w,kol) pairs x 16 bl; 16 pairs per iter (4 waves x 4 quads)
    #pragma unroll 2
    for (int it = 0; it < 18; ++it) {
        int pr  = (it << 4) + (wv << 2) + qq;   // 0..287
        int w   = pr / 9;
        int kol = pr - w * 9;                   // 0..8
        int ko  = ig * 9 + kol;                 // global k-octet 0..71
        bf16x8 piece;
        #pragma unroll
        for (int j = 0; j < 8; ++j) {
            int klocal = (kol << 3) + j;        // 0..71 within i-group
            int il = klocal / 9;
            int p  = klocal - il * 9;
            int ky = p / 3;
            int kx = p - ky * 3;
            int xc = w + kx - 1;
            float v = ((unsigned)xc < 32u) ? xl[bl * 772 + il * 96 + ky * 32 + xc] : 0.0f;
            piece[j] = (__bf16)v;
        }
        int loc   = (h << 5) + w;
        int idx16 = ((ko >> 2) << 8) + (bq << 6) + ((ko & 3) << 4) + bl;
        *(bf16x8*)&P[((size_t)loc * 4608 + idx16) * 8] = piece;
    }
}

// ---------------- main GEMM v4 ----------------
__global__ __launch_bounds__(256, 3) void local2d_kernel(
    const __bf16* __restrict__ P,      // patches, fragment layout
    const float* __restrict__ weight,  // [128,32,32,64,3,3]
    const float* __restrict__ bias,    // [128,32,32]
    float* __restrict__ out)           // [64,128,32,32]
{
    __shared__ __bf16 alds[2][12288];  // 2 x 24,576 B double-buffered A

    const int tid  = threadIdx.x;
    const int lane = tid & 63;
    const int wv   = tid >> 6;
    const int wm   = wv & 1;        // m-half: frags {2wm, 2wm+1}
    const int wn   = wv >> 1;       // o-half: nt in {4wn..4wn+3}
    const int ll   = lane & 15;
    const int q    = lane >> 4;

    // bid = [hl 2][w 5][xcd 3]: XCD owns 4 h-rows; out-line-mates co-XCD.
    const int bid = blockIdx.x;
    const int xcd = bid & 7;
    const int w   = (bid >> 3) & 31;
    const int hl  = bid >> 8;
    const int h   = (xcd << 2) + hl;
    const int loc = (h << 5) + w;

    const __bf16* Ploc = P + (size_t)loc * 36864;   // 36,864 bf16 per loc

    // per-lane W fragment pointers: o = (4wn+j)*16 + ll ; k = c*192 + t*32 + q*8
    // weight offset(o,loc,k) = (o*1024 + loc)*576 + k  floats
    const float* wbase = weight + (size_t)ll * 589824 + (size_t)loc * 576 + (q << 3);
    const float* wp[4];
    #pragma unroll
    for (int j = 0; j < 4; ++j)
        wp[j] = wbase + (size_t)((wn << 2) + j) * 9437184;   // 16*1024*576

    floatx4 acc0[4], acc1[4];
    #pragma unroll
    for (int j = 0; j < 4; ++j) {
        acc0[j] = (floatx4){0.f, 0.f, 0.f, 0.f};
        acc1[j] = (floatx4){0.f, 0.f, 0.f, 0.f};
    }

    // ---- prologue: stage chunk 0 -> buf 0 (async, 24,576 B) ----
    #pragma unroll
    for (int it = 0; it < 6; ++it) {
        const __bf16* g = Ploc + ((((it << 2) + wv) << 6) | lane) * 8;
        __builtin_amdgcn_global_load_lds(
            (const __attribute__((address_space(1))) unsigned int*)g,
            (__attribute__((address_space(3))) unsigned int*)&alds[0][(((it << 2) + wv) << 6) * 8],
            16, 0, 0);
    }
    __syncthreads();

    #pragma unroll
    for (int c = 0; c < 3; ++c) {
        // ---- issue next chunk's A while computing this one ----
        if (c < 2) {
            #pragma unroll
            for (int it = 0; it < 6; ++it) {
                const __bf16* g = Ploc + (c + 1) * 12288 + ((((it << 2) + wv) << 6) | lane) * 8;
                __builtin_amdgcn_global_load_lds(
                    (const __attribute__((address_space(1))) unsigned int*)g,
                    (__attribute__((address_space(3))) unsigned int*)&alds[(c + 1) & 1][(((it << 2) + wv) << 6) * 8],
                    16, 0, 0);
            }
        }

        // ---- 3-stage rotating W pipeline: preload t=0, t=1 ----
        floatx4 sva[3][4], svb[3][4];   // all indices compile-time under unroll
        #pragma unroll
        for (int s = 0; s < 2; ++s) {
            #pragma unroll
            for (int j = 0; j < 4; ++j) {
                const float* src = wp[j] + c * 192 + s * 32;
                sva[s][j] = *(const floatx4*)src;
                svb[s][j] = *(const floatx4*)(src + 4);
            }
        }

        // ---- K loop: 6 steps of K=32; consume slot t%3, load slot (t+2)%3 ----
        #pragma unroll
        for (int t = 0; t < 6; ++t) {
            bf16x8 af0 = *(const bf16x8*)&alds[c & 1][((((t << 2) + (wm << 1)) << 6) | lane) * 8];
            bf16x8 af1 = *(const bf16x8*)&alds[c & 1][((((t << 2) + (wm << 1) + 1) << 6) | lane) * 8];
            if (t < 4) {   // issue t+2's loads BEFORE t's MFMAs (distance 2)
                #pragma unroll
                for (int j = 0; j < 4; ++j) {
                    const float* src = wp[j] + c * 192 + (t + 2) * 32;
                    sva[(t + 2) % 3][j] = *(const floatx4*)src;
                    svb[(t + 2) % 3][j] = *(const floatx4*)(src + 4);
                }
            }
            #pragma unroll
            for (int j = 0; j < 4; ++j) {
                bf16x8 bw = cvt8(sva[t % 3][j], svb[t % 3][j]);
                acc0[j] = __builtin_amdgcn_mfma_f32_16x16x32_bf16(af0, bw, acc0[j], 0, 0, 0);
                acc1[j] = __builtin_amdgcn_mfma_f32_16x16x32_bf16(af1, bw, acc1[j], 0, 0, 0);
            }
        }
        if (c < 2) __syncthreads();   // buf[c^1] staged; buf[c] free for overwrite
    }

    // ---- epilogue: C/D col=lane&15 -> o, row=q*4+r -> b ----
    #pragma unroll
    for (int fi = 0; fi < 2; ++fi) {
        #pragma unroll
        for (int j = 0; j < 4; ++j) {
            int o = (((wn << 2) + j) << 4) + ll;
            float bv = bias[((size_t)o << 10) + loc];
            #pragma unroll
            for (int r = 0; r < 4; ++r) {
                int m = (((wm << 1) + fi) << 4) + (q << 2) + r;
                float v = (fi == 0 ? acc0[j][r] : acc1[j][r]) + bv;
                out[(((size_t)m << 7) + o) * 1024 + loc] = v;
            }
        }
    }
}

extern "C" void kernel_launch(void* const* d_in, const int* in_sizes, int n_in,
                              void* d_out, int out_size, void* d_ws, size_t ws_size,
                              hipStream_t stream) {
    const float* x  = (const float*)d_in[0];
    const float* wt = (const float*)d_in[1];
    const float* bi = (const float*)d_in[2];
    float* out = (float*)d_out;
    __bf16* P = (__bf16*)d_ws;   // needs 75,497,472 B
    prep_kernel<<<dim3(1024), dim3(256), 0, stream>>>(x, P);
    local2d_kernel<<<dim3(1024), dim3(256), 0, stream>>>(P, wt, bi, out);
}